// Round 12
// baseline (180.701 us; speedup 1.0000x reference)
//
#include <hip/hip_runtime.h>
#include <stdint.h>

#define M_NODES 2048
#define KSEL 16
#define BATCH 16
#define DBIAS 16.0f  // packed w = |n|^2 + DBIAS; key value = d^2 + (DBIAS - |p|^2) > 0

typedef unsigned int u32;

// compare-exchange ascending (explicit min/max -> v_min_u32/v_max_u32)
#define CE_ASC(x, y)                    \
  {                                     \
    u32 _a = (x), _b = (y);             \
    (x) = min(_a, _b);                  \
    (y) = max(_a, _b);                  \
  }

// Batcher odd-even mergesort, ascending, static indices. n=16: 63 CE; n=32: 191 CE.
template <int NQ>
__device__ __forceinline__ void oems_sort(u32* s) {
#pragma unroll
  for (int p = 1; p < NQ; p <<= 1) {
#pragma unroll
    for (int k = p; k >= 1; k >>= 1) {
#pragma unroll
      for (int j = k & (p - 1); j + k < NQ; j += 2 * k) {
#pragma unroll
        for (int i = 0; i < k; ++i) {
          if ((i + j) / (2 * p) == (i + j + k) / (2 * p)) {
            CE_ASC(s[i + j], s[i + j + k])
          }
        }
      }
    }
  }
}

// merge sorted-asc batch s[16] into sorted-asc a[16] (keep 16 smallest of union)
__device__ __forceinline__ void merge_into(u32 a[KSEL], const u32 s[KSEL]) {
#pragma unroll
  for (int i = 0; i < KSEL; ++i) {
    u32 sv = s[KSEL - 1 - i];
    a[i] = min(a[i], sv);  // a becomes bitonic
  }
#pragma unroll
  for (int st = 8; st >= 1; st >>= 1) {  // bitonic clean-up -> ascending
#pragma unroll
    for (int i = 0; i < KSEL; ++i) {
      if ((i & st) == 0) {
        CE_ASC(a[i], a[i + st])
      }
    }
  }
}

// biased key -> true distance: d^2 = key_f + (pp - DBIAS); clamp + sqrt + floor
__device__ __forceinline__ float key_to_dist(u32 k, float c /* = pp-DBIAS */) {
  float kf = __uint_as_float(k & 0xFFFFF800u);
  float d2 = fmaxf(kf + c, 0.0f);
  return fmaxf(sqrtf(d2), 1e-6f);
}

// ---- exact single-point scan producing BIASED keys (fallback paths only) ----
__device__ __forceinline__ void select_scalar(float px, float py, float pz,
                                              const float* __restrict__ nodes,
                                              u32 a[KSEL], int jbase,
                                              int nbatch) {
  float pp = fmaf(px, px, fmaf(py, py, pz * pz));
  float cb = DBIAS - pp;  // key value = d^2 + cb
#pragma unroll
  for (int t = 0; t < KSEL; ++t) a[t] = 0xFFFFFFFFu;
#pragma unroll 1
  for (int b = 0; b < nbatch; ++b) {
    int j0 = jbase + BATCH * b;
    const float* np = nodes + 3 * j0;
    u32 s[BATCH];
#pragma unroll
    for (int u = 0; u < BATCH; ++u) {
      float nx = np[3 * u + 0], ny = np[3 * u + 1], nz = np[3 * u + 2];
      float dx = px - nx, dy = py - ny, dz = pz - nz;
      float d2 = fmaf(dx, dx, fmaf(dy, dy, dz * dz)) + cb;
      s[u] = (__float_as_uint(d2) & 0xFFFFF800u) | (u32)(j0 + u);
    }
    oems_sort<BATCH>(s);
    merge_into(a, s);
  }
}

// ---- kernel 0: pack nodes as (x,y,z,|n|^2+DBIAS) ----
__global__ __launch_bounds__(256) void k_pack(const float* __restrict__ nodes,
                                              float4* __restrict__ packed) {
  int i = blockIdx.x * blockDim.x + threadIdx.x;
  if (i < M_NODES) {
    float x = nodes[3 * i + 0], y = nodes[3 * i + 1], z = nodes[3 * i + 2];
    packed[i] = make_float4(x, y, z, fmaf(x, x, fmaf(y, y, z * z)) + DBIAS);
  }
}

// ---- kernel 1: block = 64 points x 4 waves; wave w scans packed nodes
// [512w, 512w+512). Node stream goes down the VMEM path (not SMEM): the
// uniform batch index is laundered through a VGPR so the compiler emits
// global_load_dwordx4 (uniform addr -> single L1 transaction, broadcast;
// 32KB packed array stays hot in the 32KB L1; vmcnt is counted ->
// compiler pipelines the 16 loads per batch instead of lgkmcnt(0)-draining).
template <bool STORE>
__global__ __launch_bounds__(256, 4) void k_select(
    const float* __restrict__ means, const float4* __restrict__ packed,
    u32* __restrict__ keys_out, float* __restrict__ sum_ptr, int N) {
  __shared__ u32 lists[3][64][KSEL + 1];

  int lane = threadIdx.x & 63;
  int w = __builtin_amdgcn_readfirstlane((int)(threadIdx.x >> 6));
  int n = blockIdx.x * 64 + lane;

  float px = means[3 * n + 0];
  float py = means[3 * n + 1];
  float pz = means[3 * n + 2];
  float m2x = -2.0f * px, m2y = -2.0f * py, m2z = -2.0f * pz;
  float pp = fmaf(px, px, fmaf(py, py, pz * pz));
  const u32 HMASK = 0xFFFFF800u;

  // substream top-2 registers (all statically indexed)
  u32 t0[BATCH], t1[BATCH];
#pragma unroll
  for (int u = 0; u < BATCH; ++u) { t0[u] = 0xFFFFFFFFu; t1[u] = 0xFFFFFFFFu; }

  int jbase = 512 * w;  // wave-uniform slice
#pragma unroll 1
  for (int b = 0; b < 512 / BATCH; ++b) {
    int j0 = jbase + BATCH * b;
    u32 j0v;  // launder uniform index into a VGPR -> forces VMEM path
    asm("v_mov_b32 %0, %1" : "=v"(j0v) : "s"(j0));
    const float4* np = packed + j0v;  // VGPR base + imm offsets
#pragma unroll
    for (int u = 0; u < BATCH; ++u) {
      float4 nd = np[u];  // global_load_dwordx4, vmcnt-pipelined, L1 broadcast
      // biased d2 = d^2 + (DBIAS - |p|^2) > 0, monotone in d^2 per point
      float d2 = fmaf(nd.x, m2x, fmaf(nd.y, m2y, fmaf(nd.z, m2z, nd.w)));
      u32 key = (__float_as_uint(d2) & HMASK) | (u32)(j0 + u);
      // branch-free top-2 insert: t0<=t1 invariant -> med3 is new t1
      t1[u] = min(max(t0[u], key), t1[u]);  // v_med3_u32
      t0[u] = min(t0[u], key);
    }
  }

  // exact top-16 of the 32 candidates
  u32 cand[2 * BATCH];
#pragma unroll
  for (int u = 0; u < BATCH; ++u) {
    cand[2 * u + 0] = t0[u];
    cand[2 * u + 1] = t1[u];
  }
  oems_sort<2 * BATCH>(cand);
  u32 a[KSEL];
#pragma unroll
  for (int t = 0; t < KSEL; ++t) a[t] = cand[t];

  if (w != 0) {
#pragma unroll
    for (int t = 0; t < KSEL; ++t) lists[w - 1][lane][t] = a[t];
  }
  __syncthreads();
  if (w != 0) return;  // waves 1..3 done

  // wave 0: merge the 3 partner lists -> global top-16 per point
  // (same point per lane across waves -> same bias -> order consistent)
#pragma unroll 1
  for (int i = 0; i < 3; ++i) {
    u32 b2[KSEL];
#pragma unroll
    for (int t = 0; t < KSEL; ++t) b2[t] = lists[i][lane][t];
    merge_into(a, b2);
  }

  if (STORE) {
    u32* kp = keys_out + (size_t)n * KSEL;
#pragma unroll
    for (int t = 0; t < KSEL; t += 4) {
      *reinterpret_cast<uint4*>(kp + t) =
          make_uint4(a[t], a[t + 1], a[t + 2], a[t + 3]);
    }
  }

  float c = pp - DBIAS;
  float s = 0.0f;
#pragma unroll
  for (int t = 0; t < KSEL; ++t) s += key_to_dist(a[t], c);
#pragma unroll
  for (int off = 32; off > 0; off >>= 1) s += __shfl_xor(s, off);
  if (lane == 0) atomicAdd(sum_ptr, s);
}

// ---- kernel 2: global scale -> softmax -> gather offsets -> output ----
template <bool RELOAD>
__global__ __launch_bounds__(256) void k_finish(
    const float* __restrict__ means, const float* __restrict__ nodes,
    const float* __restrict__ noffs, const int* __restrict__ tptr,
    const u32* __restrict__ keys, const float* __restrict__ sum_ptr,
    float* __restrict__ out, int N) {
  __shared__ float4 so[M_NODES];
  int ti = *tptr;
  {
    const float* src = noffs + (size_t)ti * (3 * M_NODES);
    for (int i = threadIdx.x; i < M_NODES; i += blockDim.x) {
      so[i] = make_float4(src[3 * i + 0], src[3 * i + 1], src[3 * i + 2], 0.0f);
    }
  }
  __syncthreads();

  int n = blockIdx.x * blockDim.x + threadIdx.x;
  float px = means[3 * n + 0];
  float py = means[3 * n + 1];
  float pz = means[3 * n + 2];
  float pp = fmaf(px, px, fmaf(py, py, pz * pz));
  float c = pp - DBIAS;

  u32 a[KSEL];
  if constexpr (!RELOAD) {
    // fallback (ws too small for key spill): full exact rescan (biased keys)
    select_scalar(px, py, pz, nodes, a, 0, M_NODES / BATCH);
  } else {
    const uint4* kp = reinterpret_cast<const uint4*>(keys + (size_t)n * KSEL);
#pragma unroll
    for (int t = 0; t < 4; ++t) {
      uint4 v = kp[t];
      a[4 * t + 0] = v.x; a[4 * t + 1] = v.y;
      a[4 * t + 2] = v.z; a[4 * t + 3] = v.w;
    }
  }

  float scale = (*sum_ptr) * (1.0f / ((float)N * (float)KSEL)) + 1e-6f;
  float inv = 1.0f / scale;
  float vmin = key_to_dist(a[0], c);  // a[] sorted ascending -> a[0] is min

  float wsum = 0.0f, mx = 0.0f, my = 0.0f, mz = 0.0f;
#pragma unroll
  for (int t = 0; t < KSEL; ++t) {
    u32 k = a[t];
    float v = key_to_dist(k, c);
    float e = __expf((vmin - v) * inv);  // softmax(-v/scale), max-shifted
    float4 o = so[k & 0x7FFu];
    wsum += e;
    mx = fmaf(e, o.x, mx);
    my = fmaf(e, o.y, my);
    mz = fmaf(e, o.z, mz);
  }
  float r = 1.0f / wsum;
  out[3 * n + 0] = px + mx * r;
  out[3 * n + 1] = py + my * r;
  out[3 * n + 2] = pz + mz * r;
}

// ---- exact old-style kernel (no packed buffer available) ----
__global__ __launch_bounds__(256, 8) void k_select_nows(
    const float* __restrict__ means, const float* __restrict__ nodes,
    float* __restrict__ sum_ptr, int N) {
  __shared__ u32 lists[3][64][KSEL + 1];
  int lane = threadIdx.x & 63;
  int w = __builtin_amdgcn_readfirstlane((int)(threadIdx.x >> 6));
  int n = blockIdx.x * 64 + lane;
  float px = means[3 * n + 0], py = means[3 * n + 1], pz = means[3 * n + 2];
  float pp = fmaf(px, px, fmaf(py, py, pz * pz));
  u32 a[KSEL];
  select_scalar(px, py, pz, nodes, a, 512 * w, 512 / BATCH);
  if (w != 0) {
#pragma unroll
    for (int t = 0; t < KSEL; ++t) lists[w - 1][lane][t] = a[t];
  }
  __syncthreads();
  if (w != 0) return;
#pragma unroll 1
  for (int i = 0; i < 3; ++i) {
    u32 b2[KSEL];
#pragma unroll
    for (int t = 0; t < KSEL; ++t) b2[t] = lists[i][lane][t];
    merge_into(a, b2);
  }
  float c = pp - DBIAS;
  float s = 0.0f;
#pragma unroll
  for (int t = 0; t < KSEL; ++t) s += key_to_dist(a[t], c);
#pragma unroll
  for (int off = 32; off > 0; off >>= 1) s += __shfl_xor(s, off);
  if (lane == 0) atomicAdd(sum_ptr, s);
}

extern "C" void kernel_launch(void* const* d_in, const int* in_sizes, int n_in,
                              void* d_out, int out_size, void* d_ws,
                              size_t ws_size, hipStream_t stream) {
  const float* means = (const float*)d_in[0];
  const float* nodes = (const float*)d_in[1];
  const float* noffs = (const float*)d_in[2];
  const int* tptr = (const int*)d_in[3];
  int N = in_sizes[0] / 3;  // 131072

  // d_ws layout: [0,256) sum | [256, 256+32K) packed nodes | keys
  float* sum_ptr = (float*)d_ws;
  float4* packed = (float4*)((char*)d_ws + 256);
  u32* keys = (u32*)((char*)d_ws + 256 + M_NODES * sizeof(float4));
  size_t need_pack = 256 + M_NODES * sizeof(float4);
  size_t need_full = need_pack + (size_t)N * KSEL * sizeof(u32);

  size_t zbytes = ws_size < 256 ? ws_size : 256;
  if (zbytes) hipMemsetAsync(d_ws, 0, zbytes, stream);

  dim3 blk(256);
  dim3 grid_sel((unsigned)((N + 63) / 64));   // 64 points per block
  dim3 grid_fin((unsigned)((N + 255) / 256));
  float* out = (float*)d_out;

  if (ws_size >= need_full) {
    k_pack<<<dim3(8), blk, 0, stream>>>(nodes, packed);
    k_select<true><<<grid_sel, blk, 0, stream>>>(means, packed, keys, sum_ptr, N);
    k_finish<true><<<grid_fin, blk, 0, stream>>>(means, nodes, noffs, tptr,
                                                 keys, sum_ptr, out, N);
  } else {
    // minimal-ws fallback: exact scan in both kernels, no spill buffers
    k_select_nows<<<grid_sel, blk, 0, stream>>>(means, nodes, sum_ptr, N);
    k_finish<false><<<grid_fin, blk, 0, stream>>>(means, nodes, noffs, tptr,
                                                  keys, sum_ptr, out, N);
  }
}

// Round 13
// 98.820 us; speedup vs baseline: 1.8286x; 1.8286x over previous
//
#include <hip/hip_runtime.h>
#include <stdint.h>

#define M_NODES 2048
#define KSEL 16
#define BATCH 16
#define DBIAS 16.0f  // packed w = |n|^2 + DBIAS; key value = d^2 + (DBIAS - |p|^2) > 0

typedef unsigned int u32;

// compare-exchange ascending (explicit min/max -> v_min_u32/v_max_u32)
#define CE_ASC(x, y)                    \
  {                                     \
    u32 _a = (x), _b = (y);             \
    (x) = min(_a, _b);                  \
    (y) = max(_a, _b);                  \
  }

// Batcher odd-even mergesort, ascending, static indices. n=16: 63 CE; n=32: 191 CE.
template <int NQ>
__device__ __forceinline__ void oems_sort(u32* s) {
#pragma unroll
  for (int p = 1; p < NQ; p <<= 1) {
#pragma unroll
    for (int k = p; k >= 1; k >>= 1) {
#pragma unroll
      for (int j = k & (p - 1); j + k < NQ; j += 2 * k) {
#pragma unroll
        for (int i = 0; i < k; ++i) {
          if ((i + j) / (2 * p) == (i + j + k) / (2 * p)) {
            CE_ASC(s[i + j], s[i + j + k])
          }
        }
      }
    }
  }
}

// merge sorted-asc batch s[16] into sorted-asc a[16] (keep 16 smallest of union)
__device__ __forceinline__ void merge_into(u32 a[KSEL], const u32 s[KSEL]) {
#pragma unroll
  for (int i = 0; i < KSEL; ++i) {
    u32 sv = s[KSEL - 1 - i];
    a[i] = min(a[i], sv);  // a becomes bitonic
  }
#pragma unroll
  for (int st = 8; st >= 1; st >>= 1) {  // bitonic clean-up -> ascending
#pragma unroll
    for (int i = 0; i < KSEL; ++i) {
      if ((i & st) == 0) {
        CE_ASC(a[i], a[i + st])
      }
    }
  }
}

// biased key -> true distance: d^2 = key_f + (pp - DBIAS); clamp + sqrt + floor
__device__ __forceinline__ float key_to_dist(u32 k, float c /* = pp-DBIAS */) {
  float kf = __uint_as_float(k & 0xFFFFF800u);
  float d2 = fmaxf(kf + c, 0.0f);
  return fmaxf(sqrtf(d2), 1e-6f);
}

// ---- exact single-point scan producing BIASED keys (fallback paths only) ----
__device__ __forceinline__ void select_scalar(float px, float py, float pz,
                                              const float* __restrict__ nodes,
                                              u32 a[KSEL], int jbase,
                                              int nbatch) {
  float pp = fmaf(px, px, fmaf(py, py, pz * pz));
  float cb = DBIAS - pp;  // key value = d^2 + cb
#pragma unroll
  for (int t = 0; t < KSEL; ++t) a[t] = 0xFFFFFFFFu;
#pragma unroll 1
  for (int b = 0; b < nbatch; ++b) {
    int j0 = jbase + BATCH * b;
    const float* np = nodes + 3 * j0;
    u32 s[BATCH];
#pragma unroll
    for (int u = 0; u < BATCH; ++u) {
      float nx = np[3 * u + 0], ny = np[3 * u + 1], nz = np[3 * u + 2];
      float dx = px - nx, dy = py - ny, dz = pz - nz;
      float d2 = fmaf(dx, dx, fmaf(dy, dy, dz * dz)) + cb;
      s[u] = (__float_as_uint(d2) & 0xFFFFF800u) | (u32)(j0 + u);
    }
    oems_sort<BATCH>(s);
    merge_into(a, s);
  }
}

// ---- kernel 0: pack nodes as (x,y,z,|n|^2+DBIAS) ----
__global__ __launch_bounds__(256) void k_pack(const float* __restrict__ nodes,
                                              float4* __restrict__ packed) {
  int i = blockIdx.x * blockDim.x + threadIdx.x;
  if (i < M_NODES) {
    float x = nodes[3 * i + 0], y = nodes[3 * i + 1], z = nodes[3 * i + 2];
    packed[i] = make_float4(x, y, z, fmaf(x, x, fmaf(y, y, z * z)) + DBIAS);
  }
}

// ---- kernel 1: block = 64 points x 4 waves; wave w scans nodes
// [512w, 512w+512) from an LDS-staged copy via wave-uniform ds_read_b128
// (same-address broadcast: conflict-free; DS completes IN-ORDER so the
// compiler emits counted lgkmcnt(N) and pipelines batch b+1's reads under
// batch b's insert VALU — unlike SMEM, whose OoO returns force lgkmcnt(0)).
// Per node ~6 VALU: 3 fma (biased dot-form d2 > 0), and_or key pack,
// med3+min substream top-2 insert.
template <bool STORE>
__global__ __launch_bounds__(256, 8) void k_select(
    const float* __restrict__ means, const float4* __restrict__ packed,
    u32* __restrict__ keys_out, float* __restrict__ sum_ptr, int N) {
  __shared__ float4 snodes[M_NODES];       // 32 KB staged node copy
  __shared__ u32 lists[3][64][KSEL + 1];   // 13 KB merge scratch

  // stage: coalesced float4 loads, 8 iters of 256 threads
  for (int i = threadIdx.x; i < M_NODES; i += 256) snodes[i] = packed[i];
  __syncthreads();

  int lane = threadIdx.x & 63;
  int w = __builtin_amdgcn_readfirstlane((int)(threadIdx.x >> 6));
  int n = blockIdx.x * 64 + lane;

  float px = means[3 * n + 0];
  float py = means[3 * n + 1];
  float pz = means[3 * n + 2];
  float m2x = -2.0f * px, m2y = -2.0f * py, m2z = -2.0f * pz;
  float pp = fmaf(px, px, fmaf(py, py, pz * pz));
  const u32 HMASK = 0xFFFFF800u;

  // substream top-2 registers (all statically indexed)
  u32 t0[BATCH], t1[BATCH];
#pragma unroll
  for (int u = 0; u < BATCH; ++u) { t0[u] = 0xFFFFFFFFu; t1[u] = 0xFFFFFFFFu; }

  int jbase = 512 * w;  // wave-uniform slice
  const float4* wslice = &snodes[jbase];
#pragma unroll 1
  for (int b = 0; b < 512 / BATCH; ++b) {
    int base = BATCH * b;
#pragma unroll
    for (int u = 0; u < BATCH; ++u) {
      float4 nd = wslice[base + u];  // ds_read_b128, uniform addr broadcast
      // biased d2 = d^2 + (DBIAS - |p|^2) > 0, monotone in d^2 per point
      float d2 = fmaf(nd.x, m2x, fmaf(nd.y, m2y, fmaf(nd.z, m2z, nd.w)));
      u32 key = (__float_as_uint(d2) & HMASK) | (u32)(jbase + base + u);
      // branch-free top-2 insert: t0<=t1 invariant -> med3 is new t1
      t1[u] = min(max(t0[u], key), t1[u]);  // v_med3_u32
      t0[u] = min(t0[u], key);
    }
  }

  // exact top-16 of the 32 candidates
  u32 cand[2 * BATCH];
#pragma unroll
  for (int u = 0; u < BATCH; ++u) {
    cand[2 * u + 0] = t0[u];
    cand[2 * u + 1] = t1[u];
  }
  oems_sort<2 * BATCH>(cand);
  u32 a[KSEL];
#pragma unroll
  for (int t = 0; t < KSEL; ++t) a[t] = cand[t];

  if (w != 0) {
#pragma unroll
    for (int t = 0; t < KSEL; ++t) lists[w - 1][lane][t] = a[t];
  }
  __syncthreads();
  if (w != 0) return;  // waves 1..3 done

  // wave 0: merge the 3 partner lists -> global top-16 per point
  // (same point per lane across waves -> same bias -> order consistent)
#pragma unroll 1
  for (int i = 0; i < 3; ++i) {
    u32 b2[KSEL];
#pragma unroll
    for (int t = 0; t < KSEL; ++t) b2[t] = lists[i][lane][t];
    merge_into(a, b2);
  }

  if (STORE) {
    u32* kp = keys_out + (size_t)n * KSEL;
#pragma unroll
    for (int t = 0; t < KSEL; t += 4) {
      *reinterpret_cast<uint4*>(kp + t) =
          make_uint4(a[t], a[t + 1], a[t + 2], a[t + 3]);
    }
  }

  float c = pp - DBIAS;
  float s = 0.0f;
#pragma unroll
  for (int t = 0; t < KSEL; ++t) s += key_to_dist(a[t], c);
#pragma unroll
  for (int off = 32; off > 0; off >>= 1) s += __shfl_xor(s, off);
  if (lane == 0) atomicAdd(sum_ptr, s);
}

// ---- kernel 2: global scale -> softmax -> gather offsets -> output ----
template <bool RELOAD>
__global__ __launch_bounds__(256) void k_finish(
    const float* __restrict__ means, const float* __restrict__ nodes,
    const float* __restrict__ noffs, const int* __restrict__ tptr,
    const u32* __restrict__ keys, const float* __restrict__ sum_ptr,
    float* __restrict__ out, int N) {
  __shared__ float4 so[M_NODES];
  int ti = *tptr;
  {
    const float* src = noffs + (size_t)ti * (3 * M_NODES);
    for (int i = threadIdx.x; i < M_NODES; i += blockDim.x) {
      so[i] = make_float4(src[3 * i + 0], src[3 * i + 1], src[3 * i + 2], 0.0f);
    }
  }
  __syncthreads();

  int n = blockIdx.x * blockDim.x + threadIdx.x;
  float px = means[3 * n + 0];
  float py = means[3 * n + 1];
  float pz = means[3 * n + 2];
  float pp = fmaf(px, px, fmaf(py, py, pz * pz));
  float c = pp - DBIAS;

  u32 a[KSEL];
  if constexpr (!RELOAD) {
    // fallback (ws too small for key spill): full exact rescan (biased keys)
    select_scalar(px, py, pz, nodes, a, 0, M_NODES / BATCH);
  } else {
    const uint4* kp = reinterpret_cast<const uint4*>(keys + (size_t)n * KSEL);
#pragma unroll
    for (int t = 0; t < 4; ++t) {
      uint4 v = kp[t];
      a[4 * t + 0] = v.x; a[4 * t + 1] = v.y;
      a[4 * t + 2] = v.z; a[4 * t + 3] = v.w;
    }
  }

  float scale = (*sum_ptr) * (1.0f / ((float)N * (float)KSEL)) + 1e-6f;
  float inv = 1.0f / scale;
  float vmin = key_to_dist(a[0], c);  // a[] sorted ascending -> a[0] is min

  float wsum = 0.0f, mx = 0.0f, my = 0.0f, mz = 0.0f;
#pragma unroll
  for (int t = 0; t < KSEL; ++t) {
    u32 k = a[t];
    float v = key_to_dist(k, c);
    float e = __expf((vmin - v) * inv);  // softmax(-v/scale), max-shifted
    float4 o = so[k & 0x7FFu];
    wsum += e;
    mx = fmaf(e, o.x, mx);
    my = fmaf(e, o.y, my);
    mz = fmaf(e, o.z, mz);
  }
  float r = 1.0f / wsum;
  out[3 * n + 0] = px + mx * r;
  out[3 * n + 1] = py + my * r;
  out[3 * n + 2] = pz + mz * r;
}

// ---- exact old-style kernel (no packed buffer available) ----
__global__ __launch_bounds__(256, 8) void k_select_nows(
    const float* __restrict__ means, const float* __restrict__ nodes,
    float* __restrict__ sum_ptr, int N) {
  __shared__ u32 lists[3][64][KSEL + 1];
  int lane = threadIdx.x & 63;
  int w = __builtin_amdgcn_readfirstlane((int)(threadIdx.x >> 6));
  int n = blockIdx.x * 64 + lane;
  float px = means[3 * n + 0], py = means[3 * n + 1], pz = means[3 * n + 2];
  float pp = fmaf(px, px, fmaf(py, py, pz * pz));
  u32 a[KSEL];
  select_scalar(px, py, pz, nodes, a, 512 * w, 512 / BATCH);
  if (w != 0) {
#pragma unroll
    for (int t = 0; t < KSEL; ++t) lists[w - 1][lane][t] = a[t];
  }
  __syncthreads();
  if (w != 0) return;
#pragma unroll 1
  for (int i = 0; i < 3; ++i) {
    u32 b2[KSEL];
#pragma unroll
    for (int t = 0; t < KSEL; ++t) b2[t] = lists[i][lane][t];
    merge_into(a, b2);
  }
  float c = pp - DBIAS;
  float s = 0.0f;
#pragma unroll
  for (int t = 0; t < KSEL; ++t) s += key_to_dist(a[t], c);
#pragma unroll
  for (int off = 32; off > 0; off >>= 1) s += __shfl_xor(s, off);
  if (lane == 0) atomicAdd(sum_ptr, s);
}

extern "C" void kernel_launch(void* const* d_in, const int* in_sizes, int n_in,
                              void* d_out, int out_size, void* d_ws,
                              size_t ws_size, hipStream_t stream) {
  const float* means = (const float*)d_in[0];
  const float* nodes = (const float*)d_in[1];
  const float* noffs = (const float*)d_in[2];
  const int* tptr = (const int*)d_in[3];
  int N = in_sizes[0] / 3;  // 131072

  // d_ws layout: [0,256) sum | [256, 256+32K) packed nodes | keys
  float* sum_ptr = (float*)d_ws;
  float4* packed = (float4*)((char*)d_ws + 256);
  u32* keys = (u32*)((char*)d_ws + 256 + M_NODES * sizeof(float4));
  size_t need_pack = 256 + M_NODES * sizeof(float4);
  size_t need_full = need_pack + (size_t)N * KSEL * sizeof(u32);

  size_t zbytes = ws_size < 256 ? ws_size : 256;
  if (zbytes) hipMemsetAsync(d_ws, 0, zbytes, stream);

  dim3 blk(256);
  dim3 grid_sel((unsigned)((N + 63) / 64));   // 64 points per block
  dim3 grid_fin((unsigned)((N + 255) / 256));
  float* out = (float*)d_out;

  if (ws_size >= need_full) {
    k_pack<<<dim3(8), blk, 0, stream>>>(nodes, packed);
    k_select<true><<<grid_sel, blk, 0, stream>>>(means, packed, keys, sum_ptr, N);
    k_finish<true><<<grid_fin, blk, 0, stream>>>(means, nodes, noffs, tptr,
                                                 keys, sum_ptr, out, N);
  } else {
    // minimal-ws fallback: exact scan in both kernels, no spill buffers
    k_select_nows<<<grid_sel, blk, 0, stream>>>(means, nodes, sum_ptr, N);
    k_finish<false><<<grid_fin, blk, 0, stream>>>(means, nodes, noffs, tptr,
                                                  keys, sum_ptr, out, N);
  }
}

// Round 14
// 85.991 us; speedup vs baseline: 2.1014x; 1.1492x over previous
//
#include <hip/hip_runtime.h>
#include <stdint.h>

#define M_NODES 2048
#define KSEL 16
#define BATCH 16
#define DBIAS 16.0f  // packed w = |n|^2 + DBIAS; key value = d^2 + (DBIAS - |p|^2) > 0

typedef unsigned int u32;

// compare-exchange ascending (explicit min/max -> v_min_u32/v_max_u32)
#define CE_ASC(x, y)                    \
  {                                     \
    u32 _a = (x), _b = (y);             \
    (x) = min(_a, _b);                  \
    (y) = max(_a, _b);                  \
  }

// Batcher odd-even mergesort, ascending, static indices. n=16: 63 CE; n=32: 191 CE.
template <int NQ>
__device__ __forceinline__ void oems_sort(u32* s) {
#pragma unroll
  for (int p = 1; p < NQ; p <<= 1) {
#pragma unroll
    for (int k = p; k >= 1; k >>= 1) {
#pragma unroll
      for (int j = k & (p - 1); j + k < NQ; j += 2 * k) {
#pragma unroll
        for (int i = 0; i < k; ++i) {
          if ((i + j) / (2 * p) == (i + j + k) / (2 * p)) {
            CE_ASC(s[i + j], s[i + j + k])
          }
        }
      }
    }
  }
}

// merge sorted-asc batch s[16] into sorted-asc a[16] (keep 16 smallest of union)
__device__ __forceinline__ void merge_into(u32 a[KSEL], const u32 s[KSEL]) {
#pragma unroll
  for (int i = 0; i < KSEL; ++i) {
    u32 sv = s[KSEL - 1 - i];
    a[i] = min(a[i], sv);  // a becomes bitonic
  }
#pragma unroll
  for (int st = 8; st >= 1; st >>= 1) {  // bitonic clean-up -> ascending
#pragma unroll
    for (int i = 0; i < KSEL; ++i) {
      if ((i & st) == 0) {
        CE_ASC(a[i], a[i + st])
      }
    }
  }
}

// biased key -> true distance: d^2 = key_f + (pp - DBIAS); clamp + sqrt + floor
__device__ __forceinline__ float key_to_dist(u32 k, float c /* = pp-DBIAS */) {
  float kf = __uint_as_float(k & 0xFFFFF800u);
  float d2 = fmaxf(kf + c, 0.0f);
  return fmaxf(sqrtf(d2), 1e-6f);
}

// ---- exact single-point scan producing BIASED keys (fallback paths only) ----
__device__ __forceinline__ void select_scalar(float px, float py, float pz,
                                              const float* __restrict__ nodes,
                                              u32 a[KSEL], int jbase,
                                              int nbatch) {
  float pp = fmaf(px, px, fmaf(py, py, pz * pz));
  float cb = DBIAS - pp;  // key value = d^2 + cb
#pragma unroll
  for (int t = 0; t < KSEL; ++t) a[t] = 0xFFFFFFFFu;
#pragma unroll 1
  for (int b = 0; b < nbatch; ++b) {
    int j0 = jbase + BATCH * b;
    const float* np = nodes + 3 * j0;
    u32 s[BATCH];
#pragma unroll
    for (int u = 0; u < BATCH; ++u) {
      float nx = np[3 * u + 0], ny = np[3 * u + 1], nz = np[3 * u + 2];
      float dx = px - nx, dy = py - ny, dz = pz - nz;
      float d2 = fmaf(dx, dx, fmaf(dy, dy, dz * dz)) + cb;
      s[u] = (__float_as_uint(d2) & 0xFFFFF800u) | (u32)(j0 + u);
    }
    oems_sort<BATCH>(s);
    merge_into(a, s);
  }
}

// ---- kernel 0: pack nodes as (x,y,z,|n|^2+DBIAS) ----
__global__ __launch_bounds__(256) void k_pack(const float* __restrict__ nodes,
                                              float4* __restrict__ packed) {
  int i = blockIdx.x * blockDim.x + threadIdx.x;
  if (i < M_NODES) {
    float x = nodes[3 * i + 0], y = nodes[3 * i + 1], z = nodes[3 * i + 2];
    packed[i] = make_float4(x, y, z, fmaf(x, x, fmaf(y, y, z * z)) + DBIAS);
  }
}

// ---- kernel 1: block = 128 points x 4 waves; 2 points per lane share one
// wave-uniform scalar node stream (s_load / K$). The limiter (r10-r13
// evidence) is broadcast-path bytes/CU (~1.4 B/cyc on every path), so
// doubling points per stream halves total node traffic 64MB -> 32MB.
// Per node per point ~6 VALU: 3 fma (biased dot-form), key pack, med3+min.
template <bool STORE>
__global__ __launch_bounds__(256, 4) void k_select(
    const float* __restrict__ means, const float4* __restrict__ packed,
    u32* __restrict__ keys_out, float* __restrict__ sum_ptr, int N) {
  // [3 writer waves][128 point-slots][16 keys], padded row
  __shared__ u32 lists[3][128][KSEL + 1];

  int lane = threadIdx.x & 63;
  int w = __builtin_amdgcn_readfirstlane((int)(threadIdx.x >> 6));
  int n0 = blockIdx.x * 128 + lane;
  int n1 = n0 + 64;

  float p0x = means[3 * n0 + 0], p0y = means[3 * n0 + 1], p0z = means[3 * n0 + 2];
  float p1x = means[3 * n1 + 0], p1y = means[3 * n1 + 1], p1z = means[3 * n1 + 2];
  float a0x = -2.0f * p0x, a0y = -2.0f * p0y, a0z = -2.0f * p0z;
  float a1x = -2.0f * p1x, a1y = -2.0f * p1y, a1z = -2.0f * p1z;
  float pp0 = fmaf(p0x, p0x, fmaf(p0y, p0y, p0z * p0z));
  float pp1 = fmaf(p1x, p1x, fmaf(p1y, p1y, p1z * p1z));
  const u32 HMASK = 0xFFFFF800u;

  // substream top-2 registers for both points (statically indexed)
  u32 s0lo[BATCH], s0hi[BATCH], s1lo[BATCH], s1hi[BATCH];
#pragma unroll
  for (int u = 0; u < BATCH; ++u) {
    s0lo[u] = 0xFFFFFFFFu; s0hi[u] = 0xFFFFFFFFu;
    s1lo[u] = 0xFFFFFFFFu; s1hi[u] = 0xFFFFFFFFu;
  }

  int jbase = 512 * w;  // wave-uniform slice
#pragma unroll 1
  for (int b = 0; b < 512 / BATCH; ++b) {
    int j0 = jbase + BATCH * b;
    const float4* np = packed + j0;  // wave-uniform -> s_load streams
#pragma unroll
    for (int u = 0; u < BATCH; ++u) {
      float4 nd = np[u];  // (x,y,z,|n|^2+DBIAS) in SGPRs
      u32 tag = (u32)(j0 + u);
      // point 0
      float d20 = fmaf(nd.x, a0x, fmaf(nd.y, a0y, fmaf(nd.z, a0z, nd.w)));
      u32 k0 = (__float_as_uint(d20) & HMASK) | tag;
      s0hi[u] = min(max(s0lo[u], k0), s0hi[u]);  // v_med3_u32
      s0lo[u] = min(s0lo[u], k0);
      // point 1
      float d21 = fmaf(nd.x, a1x, fmaf(nd.y, a1y, fmaf(nd.z, a1z, nd.w)));
      u32 k1 = (__float_as_uint(d21) & HMASK) | tag;
      s1hi[u] = min(max(s1lo[u], k1), s1hi[u]);
      s1lo[u] = min(s1lo[u], k1);
    }
  }

  // exact top-16 of each point's 32 candidates
  u32 a0[KSEL], a1[KSEL];
  {
    u32 cand[2 * BATCH];
#pragma unroll
    for (int u = 0; u < BATCH; ++u) {
      cand[2 * u + 0] = s0lo[u];
      cand[2 * u + 1] = s0hi[u];
    }
    oems_sort<2 * BATCH>(cand);
#pragma unroll
    for (int t = 0; t < KSEL; ++t) a0[t] = cand[t];
#pragma unroll
    for (int u = 0; u < BATCH; ++u) {
      cand[2 * u + 0] = s1lo[u];
      cand[2 * u + 1] = s1hi[u];
    }
    oems_sort<2 * BATCH>(cand);
#pragma unroll
    for (int t = 0; t < KSEL; ++t) a1[t] = cand[t];
  }

  if (w != 0) {
#pragma unroll
    for (int t = 0; t < KSEL; ++t) {
      lists[w - 1][lane][t] = a0[t];
      lists[w - 1][lane + 64][t] = a1[t];
    }
  }
  __syncthreads();
  if (w != 0) return;  // waves 1..3 done

  // wave 0: merge the 3 partner lists -> global top-16 per point
#pragma unroll 1
  for (int i = 0; i < 3; ++i) {
    u32 b0[KSEL], b1[KSEL];
#pragma unroll
    for (int t = 0; t < KSEL; ++t) {
      b0[t] = lists[i][lane][t];
      b1[t] = lists[i][lane + 64][t];
    }
    merge_into(a0, b0);
    merge_into(a1, b1);
  }

  if (STORE) {
    u32* kp0 = keys_out + (size_t)n0 * KSEL;
    u32* kp1 = keys_out + (size_t)n1 * KSEL;
#pragma unroll
    for (int t = 0; t < KSEL; t += 4) {
      *reinterpret_cast<uint4*>(kp0 + t) =
          make_uint4(a0[t], a0[t + 1], a0[t + 2], a0[t + 3]);
      *reinterpret_cast<uint4*>(kp1 + t) =
          make_uint4(a1[t], a1[t + 1], a1[t + 2], a1[t + 3]);
    }
  }

  float c0 = pp0 - DBIAS, c1 = pp1 - DBIAS;
  float s = 0.0f;
#pragma unroll
  for (int t = 0; t < KSEL; ++t)
    s += key_to_dist(a0[t], c0) + key_to_dist(a1[t], c1);
#pragma unroll
  for (int off = 32; off > 0; off >>= 1) s += __shfl_xor(s, off);
  if (lane == 0) atomicAdd(sum_ptr, s);
}

// ---- kernel 2: global scale -> softmax -> gather offsets -> output ----
template <bool RELOAD>
__global__ __launch_bounds__(256) void k_finish(
    const float* __restrict__ means, const float* __restrict__ nodes,
    const float* __restrict__ noffs, const int* __restrict__ tptr,
    const u32* __restrict__ keys, const float* __restrict__ sum_ptr,
    float* __restrict__ out, int N) {
  __shared__ float4 so[M_NODES];
  int ti = *tptr;
  {
    const float* src = noffs + (size_t)ti * (3 * M_NODES);
    for (int i = threadIdx.x; i < M_NODES; i += blockDim.x) {
      so[i] = make_float4(src[3 * i + 0], src[3 * i + 1], src[3 * i + 2], 0.0f);
    }
  }
  __syncthreads();

  int n = blockIdx.x * blockDim.x + threadIdx.x;
  float px = means[3 * n + 0];
  float py = means[3 * n + 1];
  float pz = means[3 * n + 2];
  float pp = fmaf(px, px, fmaf(py, py, pz * pz));
  float c = pp - DBIAS;

  u32 a[KSEL];
  if constexpr (!RELOAD) {
    // fallback (ws too small for key spill): full exact rescan (biased keys)
    select_scalar(px, py, pz, nodes, a, 0, M_NODES / BATCH);
  } else {
    const uint4* kp = reinterpret_cast<const uint4*>(keys + (size_t)n * KSEL);
#pragma unroll
    for (int t = 0; t < 4; ++t) {
      uint4 v = kp[t];
      a[4 * t + 0] = v.x; a[4 * t + 1] = v.y;
      a[4 * t + 2] = v.z; a[4 * t + 3] = v.w;
    }
  }

  float scale = (*sum_ptr) * (1.0f / ((float)N * (float)KSEL)) + 1e-6f;
  float inv = 1.0f / scale;
  float vmin = key_to_dist(a[0], c);  // a[] sorted ascending -> a[0] is min

  float wsum = 0.0f, mx = 0.0f, my = 0.0f, mz = 0.0f;
#pragma unroll
  for (int t = 0; t < KSEL; ++t) {
    u32 k = a[t];
    float v = key_to_dist(k, c);
    float e = __expf((vmin - v) * inv);  // softmax(-v/scale), max-shifted
    float4 o = so[k & 0x7FFu];
    wsum += e;
    mx = fmaf(e, o.x, mx);
    my = fmaf(e, o.y, my);
    mz = fmaf(e, o.z, mz);
  }
  float r = 1.0f / wsum;
  out[3 * n + 0] = px + mx * r;
  out[3 * n + 1] = py + my * r;
  out[3 * n + 2] = pz + mz * r;
}

// ---- exact old-style kernel (no packed buffer available) ----
__global__ __launch_bounds__(256, 8) void k_select_nows(
    const float* __restrict__ means, const float* __restrict__ nodes,
    float* __restrict__ sum_ptr, int N) {
  __shared__ u32 lists[3][64][KSEL + 1];
  int lane = threadIdx.x & 63;
  int w = __builtin_amdgcn_readfirstlane((int)(threadIdx.x >> 6));
  int n = blockIdx.x * 64 + lane;
  float px = means[3 * n + 0], py = means[3 * n + 1], pz = means[3 * n + 2];
  float pp = fmaf(px, px, fmaf(py, py, pz * pz));
  u32 a[KSEL];
  select_scalar(px, py, pz, nodes, a, 512 * w, 512 / BATCH);
  if (w != 0) {
#pragma unroll
    for (int t = 0; t < KSEL; ++t) lists[w - 1][lane][t] = a[t];
  }
  __syncthreads();
  if (w != 0) return;
#pragma unroll 1
  for (int i = 0; i < 3; ++i) {
    u32 b2[KSEL];
#pragma unroll
    for (int t = 0; t < KSEL; ++t) b2[t] = lists[i][lane][t];
    merge_into(a, b2);
  }
  float c = pp - DBIAS;
  float s = 0.0f;
#pragma unroll
  for (int t = 0; t < KSEL; ++t) s += key_to_dist(a[t], c);
#pragma unroll
  for (int off = 32; off > 0; off >>= 1) s += __shfl_xor(s, off);
  if (lane == 0) atomicAdd(sum_ptr, s);
}

extern "C" void kernel_launch(void* const* d_in, const int* in_sizes, int n_in,
                              void* d_out, int out_size, void* d_ws,
                              size_t ws_size, hipStream_t stream) {
  const float* means = (const float*)d_in[0];
  const float* nodes = (const float*)d_in[1];
  const float* noffs = (const float*)d_in[2];
  const int* tptr = (const int*)d_in[3];
  int N = in_sizes[0] / 3;  // 131072

  // d_ws layout: [0,256) sum | [256, 256+32K) packed nodes | keys
  float* sum_ptr = (float*)d_ws;
  float4* packed = (float4*)((char*)d_ws + 256);
  u32* keys = (u32*)((char*)d_ws + 256 + M_NODES * sizeof(float4));
  size_t need_pack = 256 + M_NODES * sizeof(float4);
  size_t need_full = need_pack + (size_t)N * KSEL * sizeof(u32);

  size_t zbytes = ws_size < 256 ? ws_size : 256;
  if (zbytes) hipMemsetAsync(d_ws, 0, zbytes, stream);

  dim3 blk(256);
  dim3 grid_sel((unsigned)((N + 127) / 128));  // 128 points per block
  dim3 grid_fin((unsigned)((N + 255) / 256));
  float* out = (float*)d_out;

  if (ws_size >= need_full) {
    k_pack<<<dim3(8), blk, 0, stream>>>(nodes, packed);
    k_select<true><<<grid_sel, blk, 0, stream>>>(means, packed, keys, sum_ptr, N);
    k_finish<true><<<grid_fin, blk, 0, stream>>>(means, nodes, noffs, tptr,
                                                 keys, sum_ptr, out, N);
  } else {
    // minimal-ws fallback: exact scan in both kernels, no spill buffers
    dim3 grid_sel64((unsigned)((N + 63) / 64));
    k_select_nows<<<grid_sel64, blk, 0, stream>>>(means, nodes, sum_ptr, N);
    k_finish<false><<<grid_fin, blk, 0, stream>>>(means, nodes, noffs, tptr,
                                                  keys, sum_ptr, out, N);
  }
}